// Round 2
// baseline (437.606 us; speedup 1.0000x reference)
//
#include <hip/hip_runtime.h>
#include <math.h>

#define NN 10000
#define EE 160000
#define ET 170000
#define FIN 256
#define HH 8
#define CC 64
#define HC 512
#define NCLS 40

// ---------- CSR construction ----------
__global__ __launch_bounds__(256) void zero_int(int* p, int n) {
    int i = blockIdx.x * 256 + threadIdx.x;
    if (i < n) p[i] = 0;
}

__global__ __launch_bounds__(256) void hist_kernel(const int* __restrict__ ei,
                                                   int* __restrict__ deg) {
    int e = blockIdx.x * 256 + threadIdx.x;
    if (e >= ET) return;
    int d = (e < EE) ? ei[EE + e] : (e - EE);   // self-loops appended
    atomicAdd(&deg[d], 1);
}

// single-block exclusive scan over N=10000 degrees -> off[N+1], cursor copy
__global__ __launch_bounds__(1024) void scan_kernel(const int* __restrict__ deg,
                                                    int* __restrict__ off,
                                                    int* __restrict__ cursor) {
    __shared__ int sh[1024];
    int t = threadIdx.x;
    const int CH = 10;                      // ceil(10000/1024)
    int base = t * CH;
    int loc[CH];
    int sum = 0;
#pragma unroll
    for (int j = 0; j < CH; ++j) {
        int idx = base + j;
        int v = (idx < NN) ? deg[idx] : 0;
        loc[j] = sum;
        sum += v;
    }
    sh[t] = sum;
    __syncthreads();
    for (int ofs = 1; ofs < 1024; ofs <<= 1) {
        int v = (t >= ofs) ? sh[t - ofs] : 0;
        __syncthreads();
        sh[t] += v;
        __syncthreads();
    }
    int excl = sh[t] - sum;
#pragma unroll
    for (int j = 0; j < CH; ++j) {
        int idx = base + j;
        if (idx < NN) {
            int o = excl + loc[j];
            off[idx] = o;
            cursor[idx] = o;
        }
    }
    if (t == 1023) off[NN] = sh[1023];
}

__global__ __launch_bounds__(256) void scatter_kernel(const int* __restrict__ ei,
                                                      int* __restrict__ cursor,
                                                      int* __restrict__ srcs) {
    int e = blockIdx.x * 256 + threadIdx.x;
    if (e >= ET) return;
    int s, d;
    if (e < EE) { s = ei[e]; d = ei[EE + e]; }
    else        { s = e - EE; d = s; }
    int pos = atomicAdd(&cursor[d], 1);
    srcs[pos] = s;
}

// ---------- tiled fp32 GEMM: C[M,Nc] = A[M,K] @ B[K,Nc], 128x64 tile ----------
// grid.x = column blocks (Nc/64), grid.y = row blocks -> consecutive blocks
// share the same A rows (A fetched ~once from HBM).
// Optional bf16 copy of C written for the message-gather pass.
__global__ __launch_bounds__(256) void gemm_kernel(const float* __restrict__ A,
                                                   const float* __restrict__ B,
                                                   float* __restrict__ C,
                                                   unsigned short* __restrict__ Cb,
                                                   int M, int K, int Nc) {
    __shared__ float As[16][128];  // [k][m] transposed
    __shared__ float Bs[16][64];   // [k][n]
    int tid = threadIdx.x;
    int bn = blockIdx.x * 64, bm = blockIdx.y * 128;
    int tx = tid & 15, ty = tid >> 4;          // tx: 16 cols of 4, ty: 16 rows of 8
    int arow = tid >> 1, acol = (tid & 1) * 8; // A stage: 128 rows x 16 k
    int brow = tid >> 4, bcol = (tid & 15) * 4;
    float acc[8][4] = {{0.f}};
    for (int k0 = 0; k0 < K; k0 += 16) {
        float4 av0 = make_float4(0.f, 0.f, 0.f, 0.f);
        float4 av1 = make_float4(0.f, 0.f, 0.f, 0.f);
        int gr = bm + arow;
        if (gr < M) {
            const float* ap = A + (size_t)gr * K + k0 + acol;
            av0 = *(const float4*)ap;
            av1 = *(const float4*)(ap + 4);
        }
        As[acol + 0][arow] = av0.x; As[acol + 1][arow] = av0.y;
        As[acol + 2][arow] = av0.z; As[acol + 3][arow] = av0.w;
        As[acol + 4][arow] = av1.x; As[acol + 5][arow] = av1.y;
        As[acol + 6][arow] = av1.z; As[acol + 7][arow] = av1.w;

        float4 bv = make_float4(0.f, 0.f, 0.f, 0.f);
        int gc = bn + bcol;
        const float* bp = B + (size_t)(k0 + brow) * Nc;
        if (gc + 3 < Nc) {
            bv = *(const float4*)(bp + gc);
        } else {
            if (gc     < Nc) bv.x = bp[gc];
            if (gc + 1 < Nc) bv.y = bp[gc + 1];
            if (gc + 2 < Nc) bv.z = bp[gc + 2];
        }
        *(float4*)&Bs[brow][bcol] = bv;
        __syncthreads();
#pragma unroll
        for (int kk = 0; kk < 16; ++kk) {
            float4 a0 = *(const float4*)&As[kk][ty * 8];
            float4 a1 = *(const float4*)&As[kk][ty * 8 + 4];
            float4 b  = *(const float4*)&Bs[kk][tx * 4];
            float av[8] = {a0.x, a0.y, a0.z, a0.w, a1.x, a1.y, a1.z, a1.w};
            float bw[4] = {b.x, b.y, b.z, b.w};
#pragma unroll
            for (int i = 0; i < 8; ++i)
#pragma unroll
                for (int j = 0; j < 4; ++j) acc[i][j] += av[i] * bw[j];
        }
        __syncthreads();
    }
#pragma unroll
    for (int i = 0; i < 8; ++i) {
        int r = bm + ty * 8 + i;
        if (r >= M) continue;
        int c = bn + tx * 4;
        if (c + 3 < Nc) {
            *(float4*)(C + (size_t)r * Nc + c) =
                make_float4(acc[i][0], acc[i][1], acc[i][2], acc[i][3]);
            if (Cb) {
                unsigned short h[4];
#pragma unroll
                for (int j = 0; j < 4; ++j) {
                    unsigned int x = __builtin_bit_cast(unsigned int, acc[i][j]);
                    h[j] = (unsigned short)((x + 0x7FFFu + ((x >> 16) & 1u)) >> 16);
                }
                *(ushort4*)(Cb + (size_t)r * Nc + c) = make_ushort4(h[0], h[1], h[2], h[3]);
            }
        } else {
#pragma unroll
            for (int j = 0; j < 4; ++j) {
                int c2 = c + j;
                if (c2 < Nc) {
                    C[(size_t)r * Nc + c2] = acc[i][j];
                    if (Cb) {
                        unsigned int x = __builtin_bit_cast(unsigned int, acc[i][j]);
                        Cb[(size_t)r * Nc + c2] =
                            (unsigned short)((x + 0x7FFFu + ((x >> 16) & 1u)) >> 16);
                    }
                }
            }
        }
    }
}

// ---------- attention coefficients: al_s/al_d [N,H] (fp32 hx) ----------
__global__ __launch_bounds__(256) void attn_kernel(const float* __restrict__ hx,
                                                   const float* __restrict__ a_src,
                                                   const float* __restrict__ a_dst,
                                                   float* __restrict__ al_s,
                                                   float* __restrict__ al_d,
                                                   int Hh, int Cc) {
    int wave = threadIdx.x >> 6, lane = threadIdx.x & 63;
    int n = blockIdx.x * 4 + wave;
    if (n >= NN) return;
    for (int h = 0; h < Hh; ++h) {
        float vs = 0.f, vd = 0.f;
        if (lane < Cc) {
            float v = hx[((size_t)n * Hh + h) * Cc + lane];
            vs = v * a_src[h * Cc + lane];
            vd = v * a_dst[h * Cc + lane];
        }
#pragma unroll
        for (int o = 32; o; o >>= 1) {
            vs += __shfl_down(vs, o);
            vd += __shfl_down(vd, o);
        }
        if (lane == 0) {
            al_s[n * Hh + h] = vs;
            al_d[n * Hh + h] = vd;
        }
    }
}

// ---------- fused softmax+aggregate, layers 0/1 (H=8,C=64), bf16 messages ----
__global__ __launch_bounds__(256) void aggregate_kernel(const unsigned short* __restrict__ hx2,
                                                        const float* __restrict__ al_s,
                                                        const float* __restrict__ al_d,
                                                        const int* __restrict__ off,
                                                        const int* __restrict__ srcs,
                                                        const float* __restrict__ bias,
                                                        float* __restrict__ out) {
    int n = blockIdx.x;
    int tid = threadIdx.x;
    int ch = tid * 2;
    int h = ch >> 6;
    float ald = al_d[n * HH + h];
    int i0 = off[n], i1 = off[n + 1];
    float a0 = 0.f, a1 = 0.f, den = 0.f;
    for (int i = i0; i < i1; ++i) {
        int s = srcs[i];
        float e = al_s[s * HH + h] + ald;
        e = e > 0.f ? e : 0.2f * e;           // leaky_relu
        float w = __expf(e);                  // logits tame -> no max-sub needed
        unsigned int v = *(const unsigned int*)(hx2 + (size_t)s * HC + ch);
        float v0 = __builtin_bit_cast(float, v << 16);
        float v1 = __builtin_bit_cast(float, v & 0xFFFF0000u);
        a0 += w * v0;
        a1 += w * v1;
        den += w;
    }
    float inv = 1.f / (den + 1e-16f);
    float o0 = a0 * inv + bias[ch];
    float o1 = a1 * inv + bias[ch + 1];
    o0 = o0 > 0.f ? o0 : expm1f(o0);          // ELU
    o1 = o1 > 0.f ? o1 : expm1f(o1);
    out[(size_t)n * HC + ch]     = o0;
    out[(size_t)n * HC + ch + 1] = o1;
}

// ---------- layer 2 aggregate (H=1,C=40), fp32, no ELU ----------
__global__ __launch_bounds__(64) void aggregate2_kernel(const float* __restrict__ hx,
                                                        const float* __restrict__ al_s,
                                                        const float* __restrict__ al_d,
                                                        const int* __restrict__ off,
                                                        const int* __restrict__ srcs,
                                                        const float* __restrict__ bias,
                                                        float* __restrict__ out) {
    int n = blockIdx.x;
    int c = threadIdx.x;
    float ald = al_d[n];
    int i0 = off[n], i1 = off[n + 1];
    float acc = 0.f, den = 0.f;
    for (int i = i0; i < i1; ++i) {
        int s = srcs[i];
        float e = al_s[s] + ald;
        e = e > 0.f ? e : 0.2f * e;
        float w = __expf(e);
        if (c < NCLS) acc += w * hx[(size_t)s * NCLS + c];
        den += w;
    }
    if (c < NCLS) out[(size_t)n * NCLS + c] = acc / (den + 1e-16f) + bias[c];
}

extern "C" void kernel_launch(void* const* d_in, const int* in_sizes, int n_in,
                              void* d_out, int out_size, void* d_ws, size_t ws_size,
                              hipStream_t stream) {
    const float* x   = (const float*)d_in[0];
    const int*   ei  = (const int*)  d_in[1];
    const float* W0  = (const float*)d_in[2];
    const float* as0 = (const float*)d_in[3];
    const float* ad0 = (const float*)d_in[4];
    const float* b0  = (const float*)d_in[5];
    const float* W1  = (const float*)d_in[6];
    const float* as1 = (const float*)d_in[7];
    const float* ad1 = (const float*)d_in[8];
    const float* b1  = (const float*)d_in[9];
    const float* W2  = (const float*)d_in[10];
    const float* as2 = (const float*)d_in[11];
    const float* ad2 = (const float*)d_in[12];
    const float* b2  = (const float*)d_in[13];
    float* out = (float*)d_out;

    char* p = (char*)d_ws;
    int* deg    = (int*)p; p += 40000;
    int* cursor = (int*)p; p += 40000;
    int* off    = (int*)p; p += 40016;
    int* srcs   = (int*)p; p += 680000;
    float* hx   = (float*)p; p += 20480000;
    float* fA   = (float*)p; p += 20480000;
    float* fB   = (float*)p; p += 20480000;
    unsigned short* hx2 = (unsigned short*)p; p += 10240000;
    float* alsb = (float*)p; p += 320000;
    float* aldb = (float*)p; p += 320000;

    // CSR by dst (rebuilt every call; no cross-call state)
    zero_int<<<(NN + 255) / 256, 256, 0, stream>>>(deg, NN);
    hist_kernel<<<(ET + 255) / 256, 256, 0, stream>>>(ei, deg);
    scan_kernel<<<1, 1024, 0, stream>>>(deg, off, cursor);
    scatter_kernel<<<(ET + 255) / 256, 256, 0, stream>>>(ei, cursor, srcs);

    dim3 g0(HC / 64, (NN + 127) / 128);   // column blocks on x for A reuse
    // layer 0
    gemm_kernel<<<g0, 256, 0, stream>>>(x, W0, hx, hx2, NN, FIN, HC);
    attn_kernel<<<(NN + 3) / 4, 256, 0, stream>>>(hx, as0, ad0, alsb, aldb, HH, CC);
    aggregate_kernel<<<NN, 256, 0, stream>>>(hx2, alsb, aldb, off, srcs, b0, fA);
    // layer 1
    gemm_kernel<<<g0, 256, 0, stream>>>(fA, W1, hx, hx2, NN, HC, HC);
    attn_kernel<<<(NN + 3) / 4, 256, 0, stream>>>(hx, as1, ad1, alsb, aldb, HH, CC);
    aggregate_kernel<<<NN, 256, 0, stream>>>(hx2, alsb, aldb, off, srcs, b1, fB);
    // layer 2 (fp32 throughout — keep final output precision)
    dim3 g2(1, (NN + 127) / 128);
    gemm_kernel<<<g2, 256, 0, stream>>>(fB, W2, hx, (unsigned short*)nullptr, NN, HC, NCLS);
    attn_kernel<<<(NN + 3) / 4, 256, 0, stream>>>(hx, as2, ad2, alsb, aldb, 1, NCLS);
    aggregate2_kernel<<<NN, 64, 0, stream>>>(hx, alsb, aldb, off, srcs, b2, out);
}

// Round 3
// 367.226 us; speedup vs baseline: 1.1917x; 1.1917x over previous
//
#include <hip/hip_runtime.h>
#include <math.h>

#define NN 10000
#define EE 160000
#define ET 170000
#define FIN 256
#define HH 8
#define CC 64
#define HC 512
#define NCLS 40

typedef unsigned short u16;
typedef unsigned int u32;
typedef __attribute__((ext_vector_type(8))) short bf16x8;
typedef __attribute__((ext_vector_type(4))) float f32x4;

__device__ inline u16 bf16_rne(float f) {
    u32 x = __builtin_bit_cast(u32, f);
    return (u16)((x + 0x7FFFu + ((x >> 16) & 1u)) >> 16);
}
__device__ inline float bf16_to_f(u16 h) {
    return __builtin_bit_cast(float, (u32)h << 16);
}
__device__ inline void split2(float f, u16& hi, u16& lo) {
    u16 h = bf16_rne(f);
    hi = h;
    lo = bf16_rne(f - bf16_to_f(h));
}

// ---------- CSR construction ----------
__global__ __launch_bounds__(256) void zero_int(int* p, int n) {
    int i = blockIdx.x * 256 + threadIdx.x;
    if (i < n) p[i] = 0;
}

__global__ __launch_bounds__(256) void hist_kernel(const int* __restrict__ ei,
                                                   int* __restrict__ deg) {
    int e = blockIdx.x * 256 + threadIdx.x;
    if (e >= ET) return;
    int d = (e < EE) ? ei[EE + e] : (e - EE);   // self-loops appended
    atomicAdd(&deg[d], 1);
}

__global__ __launch_bounds__(1024) void scan_kernel(const int* __restrict__ deg,
                                                    int* __restrict__ off,
                                                    int* __restrict__ cursor) {
    __shared__ int sh[1024];
    int t = threadIdx.x;
    const int CH = 10;
    int base = t * CH;
    int loc[CH];
    int sum = 0;
#pragma unroll
    for (int j = 0; j < CH; ++j) {
        int idx = base + j;
        int v = (idx < NN) ? deg[idx] : 0;
        loc[j] = sum;
        sum += v;
    }
    sh[t] = sum;
    __syncthreads();
    for (int ofs = 1; ofs < 1024; ofs <<= 1) {
        int v = (t >= ofs) ? sh[t - ofs] : 0;
        __syncthreads();
        sh[t] += v;
        __syncthreads();
    }
    int excl = sh[t] - sum;
#pragma unroll
    for (int j = 0; j < CH; ++j) {
        int idx = base + j;
        if (idx < NN) {
            int o = excl + loc[j];
            off[idx] = o;
            cursor[idx] = o;
        }
    }
    if (t == 1023) off[NN] = sh[1023];
}

__global__ __launch_bounds__(256) void scatter_kernel(const int* __restrict__ ei,
                                                      int* __restrict__ cursor,
                                                      int* __restrict__ srcs) {
    int e = blockIdx.x * 256 + threadIdx.x;
    if (e >= ET) return;
    int s, d;
    if (e < EE) { s = ei[e]; d = ei[EE + e]; }
    else        { s = e - EE; d = s; }
    int pos = atomicAdd(&cursor[d], 1);
    srcs[pos] = s;
}

// ---------- fp32 -> split-bf16 conversions ----------
__global__ __launch_bounds__(256) void split_kernel(const float* __restrict__ in,
                                                    u16* __restrict__ hi,
                                                    u16* __restrict__ lo, int n) {
    int i = blockIdx.x * 256 + threadIdx.x;
    if (i >= n) return;
    u16 h, l;
    split2(in[i], h, l);
    hi[i] = h;
    lo[i] = l;
}

// W[K][N] -> WhT/WlT [N][K]; K power of two (kshift)
__global__ __launch_bounds__(256) void splitT_kernel(const float* __restrict__ W,
                                                     u16* __restrict__ hiT,
                                                     u16* __restrict__ loT,
                                                     int kshift, int N) {
    int i = blockIdx.x * 256 + threadIdx.x;
    int K = 1 << kshift;
    if (i >= (N << kshift)) return;
    int n = i >> kshift;
    int k = i & (K - 1);
    u16 h, l;
    split2(W[(size_t)k * N + n], h, l);
    hiT[i] = h;
    loT[i] = l;
}

// ---------- split-bf16 MFMA GEMM: C[M,Nc] = (Ah+Al)[M,K] x (Bh+Bl)^T ----------
// BhT/BlT are [Nc][K] (k-contiguous). Tile 128x64, BK=32, 256 threads = 4 waves.
// C (fp32) and/or Cb (bf16) outputs optional.
__global__ __launch_bounds__(256) void gemm_mfma(const u16* __restrict__ Ah,
                                                 const u16* __restrict__ Al,
                                                 const u16* __restrict__ BhT,
                                                 const u16* __restrict__ BlT,
                                                 float* __restrict__ C,
                                                 u16* __restrict__ Cb,
                                                 int M, int K, int Nc) {
    __shared__ u16 Ahs[128 * 40];   // [m][k] stride 40 (pad: 2-way banks = free)
    __shared__ u16 Als[128 * 40];
    __shared__ u16 Bhs[64 * 40];    // [n][k]
    __shared__ u16 Bls[64 * 40];
    int t = threadIdx.x;
    int bn = blockIdx.x * 64, bm = blockIdx.y * 128;

    int arow = t >> 1, akoff = (t & 1) * 16;
    int brow = t & 63, bkoff = (t >> 6) * 8;
    bool a_ok = (bm + arow) < M;
    bool b_ok = (bn + brow) < Nc;
    const u16* Aph = Ah + (size_t)(bm + arow) * K + akoff;
    const u16* Apl = Al + (size_t)(bm + arow) * K + akoff;
    const u16* Bph = BhT + (size_t)(bn + brow) * K + bkoff;
    const u16* Bpl = BlT + (size_t)(bn + brow) * K + bkoff;

    int lane = t & 63, w = t >> 6;
    int fm = lane & 15, ks = (lane >> 4) * 8;

    f32x4 acc[2][4] = {};
    uint4 ra0h, ra1h, ra0l, ra1l, rbh, rbl;

#define LOAD_STAGE(k0)                                                        \
    {                                                                         \
        uint4 z = make_uint4(0u, 0u, 0u, 0u);                                 \
        ra0h = ra1h = ra0l = ra1l = z; rbh = rbl = z;                         \
        if (a_ok) {                                                           \
            ra0h = *(const uint4*)(Aph + (k0));                               \
            ra1h = *(const uint4*)(Aph + (k0) + 8);                           \
            ra0l = *(const uint4*)(Apl + (k0));                               \
            ra1l = *(const uint4*)(Apl + (k0) + 8);                           \
        }                                                                     \
        if (b_ok) {                                                           \
            rbh = *(const uint4*)(Bph + (k0));                                \
            rbl = *(const uint4*)(Bpl + (k0));                                \
        }                                                                     \
    }

    LOAD_STAGE(0)
    for (int k0 = 0; k0 < K; k0 += 32) {
        *(uint4*)&Ahs[arow * 40 + akoff]     = ra0h;
        *(uint4*)&Ahs[arow * 40 + akoff + 8] = ra1h;
        *(uint4*)&Als[arow * 40 + akoff]     = ra0l;
        *(uint4*)&Als[arow * 40 + akoff + 8] = ra1l;
        *(uint4*)&Bhs[brow * 40 + bkoff] = rbh;
        *(uint4*)&Bls[brow * 40 + bkoff] = rbl;
        __syncthreads();
        if (k0 + 32 < K) LOAD_STAGE(k0 + 32)   // prefetch overlaps MFMA below
        bf16x8 ah0 = *(const bf16x8*)&Ahs[(w * 32 + fm) * 40 + ks];
        bf16x8 ah1 = *(const bf16x8*)&Ahs[(w * 32 + 16 + fm) * 40 + ks];
        bf16x8 al0 = *(const bf16x8*)&Als[(w * 32 + fm) * 40 + ks];
        bf16x8 al1 = *(const bf16x8*)&Als[(w * 32 + 16 + fm) * 40 + ks];
#pragma unroll
        for (int tn = 0; tn < 4; ++tn) {
            bf16x8 bh = *(const bf16x8*)&Bhs[(tn * 16 + fm) * 40 + ks];
            bf16x8 bl = *(const bf16x8*)&Bls[(tn * 16 + fm) * 40 + ks];
            acc[0][tn] = __builtin_amdgcn_mfma_f32_16x16x32_bf16(ah0, bh, acc[0][tn], 0, 0, 0);
            acc[0][tn] = __builtin_amdgcn_mfma_f32_16x16x32_bf16(al0, bh, acc[0][tn], 0, 0, 0);
            acc[0][tn] = __builtin_amdgcn_mfma_f32_16x16x32_bf16(ah0, bl, acc[0][tn], 0, 0, 0);
            acc[1][tn] = __builtin_amdgcn_mfma_f32_16x16x32_bf16(ah1, bh, acc[1][tn], 0, 0, 0);
            acc[1][tn] = __builtin_amdgcn_mfma_f32_16x16x32_bf16(al1, bh, acc[1][tn], 0, 0, 0);
            acc[1][tn] = __builtin_amdgcn_mfma_f32_16x16x32_bf16(ah1, bl, acc[1][tn], 0, 0, 0);
        }
        __syncthreads();
    }
#undef LOAD_STAGE

    // C/D layout: col = lane&15, row = (lane>>4)*4 + reg  [verified m89/m91]
#pragma unroll
    for (int tm = 0; tm < 2; ++tm) {
#pragma unroll
        for (int tn = 0; tn < 4; ++tn) {
            int gcol = bn + tn * 16 + fm;
            if (gcol >= Nc) continue;
            int grow = bm + w * 32 + tm * 16 + (lane >> 4) * 4;
#pragma unroll
            for (int r = 0; r < 4; ++r) {
                if (grow + r < M) {
                    float v = acc[tm][tn][r];
                    if (C)  C[(size_t)(grow + r) * Nc + gcol] = v;
                    if (Cb) Cb[(size_t)(grow + r) * Nc + gcol] = bf16_rne(v);
                }
            }
        }
    }
}

// ---------- attention coefficients from bf16 hx2 (H=8, C=64) ----------
__global__ __launch_bounds__(256) void attn_bf16_kernel(const u16* __restrict__ hx2,
                                                        const float* __restrict__ a_src,
                                                        const float* __restrict__ a_dst,
                                                        float* __restrict__ al_s,
                                                        float* __restrict__ al_d) {
    int wave = threadIdx.x >> 6, lane = threadIdx.x & 63;
    int n = blockIdx.x * 4 + wave;
    if (n >= NN) return;
    for (int h = 0; h < HH; ++h) {
        float v = bf16_to_f(hx2[(size_t)n * HC + h * CC + lane]);
        float vs = v * a_src[h * CC + lane];
        float vd = v * a_dst[h * CC + lane];
#pragma unroll
        for (int o = 32; o; o >>= 1) {
            vs += __shfl_down(vs, o);
            vd += __shfl_down(vd, o);
        }
        if (lane == 0) {
            al_s[n * HH + h] = vs;
            al_d[n * HH + h] = vd;
        }
    }
}

// ---------- fp32 attention coefficients (layer 2: H=1, C=40) ----------
__global__ __launch_bounds__(256) void attn_f32_kernel(const float* __restrict__ hx,
                                                       const float* __restrict__ a_src,
                                                       const float* __restrict__ a_dst,
                                                       float* __restrict__ al_s,
                                                       float* __restrict__ al_d,
                                                       int Hh, int Cc) {
    int wave = threadIdx.x >> 6, lane = threadIdx.x & 63;
    int n = blockIdx.x * 4 + wave;
    if (n >= NN) return;
    for (int h = 0; h < Hh; ++h) {
        float vs = 0.f, vd = 0.f;
        if (lane < Cc) {
            float v = hx[((size_t)n * Hh + h) * Cc + lane];
            vs = v * a_src[h * Cc + lane];
            vd = v * a_dst[h * Cc + lane];
        }
#pragma unroll
        for (int o = 32; o; o >>= 1) {
            vs += __shfl_down(vs, o);
            vd += __shfl_down(vd, o);
        }
        if (lane == 0) {
            al_s[n * Hh + h] = vs;
            al_d[n * Hh + h] = vd;
        }
    }
}

// ---------- fused softmax+aggregate+ELU, emits next layer's split-bf16 A ----
__global__ __launch_bounds__(256) void aggregate_kernel(const u16* __restrict__ hx2,
                                                        const float* __restrict__ al_s,
                                                        const float* __restrict__ al_d,
                                                        const int* __restrict__ off,
                                                        const int* __restrict__ srcs,
                                                        const float* __restrict__ bias,
                                                        u16* __restrict__ outh,
                                                        u16* __restrict__ outl) {
    int n = blockIdx.x;
    int tid = threadIdx.x;
    int ch = tid * 2;
    int h = ch >> 6;
    float ald = al_d[n * HH + h];
    int i0 = off[n], i1 = off[n + 1];
    float a0 = 0.f, a1 = 0.f, den = 0.f;
    for (int i = i0; i < i1; ++i) {
        int s = srcs[i];
        float e = al_s[s * HH + h] + ald;
        e = e > 0.f ? e : 0.2f * e;           // leaky_relu
        float wgt = __expf(e);                // tame logits -> no max-sub
        u32 v = *(const u32*)(hx2 + (size_t)s * HC + ch);
        a0 += wgt * __builtin_bit_cast(float, v << 16);
        a1 += wgt * __builtin_bit_cast(float, v & 0xFFFF0000u);
        den += wgt;
    }
    float inv = 1.f / (den + 1e-16f);
    float o0 = a0 * inv + bias[ch];
    float o1 = a1 * inv + bias[ch + 1];
    o0 = o0 > 0.f ? o0 : expm1f(o0);          // ELU
    o1 = o1 > 0.f ? o1 : expm1f(o1);
    u16 h0, l0, h1, l1;
    split2(o0, h0, l0);
    split2(o1, h1, l1);
    *(ushort2*)&outh[(size_t)n * HC + ch] = make_ushort2(h0, h1);
    *(ushort2*)&outl[(size_t)n * HC + ch] = make_ushort2(l0, l1);
}

// ---------- layer 2 aggregate (H=1,C=40), fp32, no ELU ----------
__global__ __launch_bounds__(64) void aggregate2_kernel(const float* __restrict__ hx,
                                                        const float* __restrict__ al_s,
                                                        const float* __restrict__ al_d,
                                                        const int* __restrict__ off,
                                                        const int* __restrict__ srcs,
                                                        const float* __restrict__ bias,
                                                        float* __restrict__ out) {
    int n = blockIdx.x;
    int c = threadIdx.x;
    float ald = al_d[n];
    int i0 = off[n], i1 = off[n + 1];
    float acc = 0.f, den = 0.f;
    for (int i = i0; i < i1; ++i) {
        int s = srcs[i];
        float e = al_s[s] + ald;
        e = e > 0.f ? e : 0.2f * e;
        float wgt = __expf(e);
        if (c < NCLS) acc += wgt * hx[(size_t)s * NCLS + c];
        den += wgt;
    }
    if (c < NCLS) out[(size_t)n * NCLS + c] = acc / (den + 1e-16f) + bias[c];
}

extern "C" void kernel_launch(void* const* d_in, const int* in_sizes, int n_in,
                              void* d_out, int out_size, void* d_ws, size_t ws_size,
                              hipStream_t stream) {
    const float* x   = (const float*)d_in[0];
    const int*   ei  = (const int*)  d_in[1];
    const float* W0  = (const float*)d_in[2];
    const float* as0 = (const float*)d_in[3];
    const float* ad0 = (const float*)d_in[4];
    const float* b0  = (const float*)d_in[5];
    const float* W1  = (const float*)d_in[6];
    const float* as1 = (const float*)d_in[7];
    const float* ad1 = (const float*)d_in[8];
    const float* b1  = (const float*)d_in[9];
    const float* W2  = (const float*)d_in[10];
    const float* as2 = (const float*)d_in[11];
    const float* ad2 = (const float*)d_in[12];
    const float* b2  = (const float*)d_in[13];
    float* out = (float*)d_out;

    char* p = (char*)d_ws;
    int* deg    = (int*)p; p += 40000;
    int* cursor = (int*)p; p += 40000;
    int* off    = (int*)p; p += 40016;
    int* srcs   = (int*)p; p += 680000;
    u16* xh  = (u16*)p; p += 5120000;
    u16* xl  = (u16*)p; p += 5120000;
    u16* w0h = (u16*)p; p += 262144;
    u16* w0l = (u16*)p; p += 262144;
    u16* w1h = (u16*)p; p += 524288;
    u16* w1l = (u16*)p; p += 524288;
    u16* w2h = (u16*)p; p += 40960;
    u16* w2l = (u16*)p; p += 40960;
    u16* hx2 = (u16*)p; p += 10240000;
    u16* fAh = (u16*)p; p += 10240000;
    u16* fAl = (u16*)p; p += 10240000;
    u16* fBh = (u16*)p; p += 10240000;
    u16* fBl = (u16*)p; p += 10240000;
    float* hx40 = (float*)p; p += 1600000;
    float* alsb = (float*)p; p += 320000;
    float* aldb = (float*)p; p += 320000;

    // CSR by dst
    zero_int<<<(NN + 255) / 256, 256, 0, stream>>>(deg, NN);
    hist_kernel<<<(ET + 255) / 256, 256, 0, stream>>>(ei, deg);
    scan_kernel<<<1, 1024, 0, stream>>>(deg, off, cursor);
    scatter_kernel<<<(ET + 255) / 256, 256, 0, stream>>>(ei, cursor, srcs);

    // splits
    split_kernel<<<(NN * FIN + 255) / 256, 256, 0, stream>>>(x, xh, xl, NN * FIN);
    splitT_kernel<<<(HC * FIN + 255) / 256, 256, 0, stream>>>(W0, w0h, w0l, 8, HC);
    splitT_kernel<<<(HC * HC + 255) / 256, 256, 0, stream>>>(W1, w1h, w1l, 9, HC);
    splitT_kernel<<<(NCLS * HC + 255) / 256, 256, 0, stream>>>(W2, w2h, w2l, 9, NCLS);

    dim3 gA(HC / 64, (NN + 127) / 128);
    // layer 0
    gemm_mfma<<<gA, 256, 0, stream>>>(xh, xl, w0h, w0l, (float*)nullptr, hx2, NN, FIN, HC);
    attn_bf16_kernel<<<(NN + 3) / 4, 256, 0, stream>>>(hx2, as0, ad0, alsb, aldb);
    aggregate_kernel<<<NN, 256, 0, stream>>>(hx2, alsb, aldb, off, srcs, b0, fAh, fAl);
    // layer 1
    gemm_mfma<<<gA, 256, 0, stream>>>(fAh, fAl, w1h, w1l, (float*)nullptr, hx2, NN, HC, HC);
    attn_bf16_kernel<<<(NN + 3) / 4, 256, 0, stream>>>(hx2, as1, ad1, alsb, aldb);
    aggregate_kernel<<<NN, 256, 0, stream>>>(hx2, alsb, aldb, off, srcs, b1, fBh, fBl);
    // layer 2 (fp32 output for final precision)
    dim3 gC(1, (NN + 127) / 128);
    gemm_mfma<<<gC, 256, 0, stream>>>(fBh, fBl, w2h, w2l, hx40, (u16*)nullptr, NN, HC, NCLS);
    attn_f32_kernel<<<(NN + 3) / 4, 256, 0, stream>>>(hx40, as2, ad2, alsb, aldb, 1, NCLS);
    aggregate2_kernel<<<NN, 64, 0, stream>>>(hx40, alsb, aldb, off, srcs, b2, out);
}

// Round 4
// 286.339 us; speedup vs baseline: 1.5283x; 1.2825x over previous
//
#include <hip/hip_runtime.h>
#include <math.h>

#define NN 10000
#define EE 160000
#define ET 170000
#define FIN 256
#define HH 8
#define CC 64
#define HC 512
#define NCLS 40

typedef unsigned short u16;
typedef unsigned int u32;
typedef _Float16 f16;
using f16x8 = __attribute__((ext_vector_type(8))) _Float16;
using f32x4 = __attribute__((ext_vector_type(4))) float;

__device__ inline float h2f(u16 bits) {
    return (float)__builtin_bit_cast(f16, bits);
}

// ---------- CSR construction ----------
__global__ __launch_bounds__(256) void zero_int(int* p, int n) {
    int i = blockIdx.x * 256 + threadIdx.x;
    if (i < n) p[i] = 0;
}

__global__ __launch_bounds__(256) void hist_kernel(const int* __restrict__ ei,
                                                   int* __restrict__ deg) {
    int e = blockIdx.x * 256 + threadIdx.x;
    if (e >= ET) return;
    int d = (e < EE) ? ei[EE + e] : (e - EE);   // self-loops appended
    atomicAdd(&deg[d], 1);
}

__global__ __launch_bounds__(1024) void scan_kernel(const int* __restrict__ deg,
                                                    int* __restrict__ off,
                                                    int* __restrict__ cursor) {
    __shared__ int sh[1024];
    int t = threadIdx.x;
    const int CH = 10;
    int base = t * CH;
    int loc[CH];
    int sum = 0;
#pragma unroll
    for (int j = 0; j < CH; ++j) {
        int idx = base + j;
        int v = (idx < NN) ? deg[idx] : 0;
        loc[j] = sum;
        sum += v;
    }
    sh[t] = sum;
    __syncthreads();
    for (int ofs = 1; ofs < 1024; ofs <<= 1) {
        int v = (t >= ofs) ? sh[t - ofs] : 0;
        __syncthreads();
        sh[t] += v;
        __syncthreads();
    }
    int excl = sh[t] - sum;
#pragma unroll
    for (int j = 0; j < CH; ++j) {
        int idx = base + j;
        if (idx < NN) {
            int o = excl + loc[j];
            off[idx] = o;
            cursor[idx] = o;
        }
    }
    if (t == 1023) off[NN] = sh[1023];
}

__global__ __launch_bounds__(256) void scatter_kernel(const int* __restrict__ ei,
                                                      int* __restrict__ cursor,
                                                      int* __restrict__ srcs) {
    int e = blockIdx.x * 256 + threadIdx.x;
    if (e >= ET) return;
    int s, d;
    if (e < EE) { s = ei[e]; d = ei[EE + e]; }
    else        { s = e - EE; d = s; }
    int pos = atomicAdd(&cursor[d], 1);
    srcs[pos] = s;
}

// ---------- fp32 -> fp16 conversions ----------
__global__ __launch_bounds__(256) void conv_f16(const float* __restrict__ in,
                                                f16* __restrict__ o, int n4) {
    int i = blockIdx.x * 256 + threadIdx.x;
    if (i >= n4) return;
    float4 v = *(const float4*)(in + (size_t)i * 4);
    u16 h0 = __builtin_bit_cast(u16, (f16)v.x);
    u16 h1 = __builtin_bit_cast(u16, (f16)v.y);
    u16 h2 = __builtin_bit_cast(u16, (f16)v.z);
    u16 h3 = __builtin_bit_cast(u16, (f16)v.w);
    *(ushort4*)(o + (size_t)i * 4) = make_ushort4(h0, h1, h2, h3);
}

// W[K][N] -> WT[N][K] fp16; K = 1<<kshift
__global__ __launch_bounds__(256) void convT_f16(const float* __restrict__ W,
                                                 f16* __restrict__ oT,
                                                 int kshift, int N) {
    int i = blockIdx.x * 256 + threadIdx.x;
    int K = 1 << kshift;
    if (i >= (N << kshift)) return;
    int n = i >> kshift;
    int k = i & (K - 1);
    oT[i] = (f16)W[(size_t)k * N + n];
}

// ---------- fp16 MFMA GEMM: C[M,Nc] = A[M,K] x BT[Nc,K]^T ----------
// BM=32, full-width BN per block (grid = (1, M/32)) -> A read exactly once.
// BN=512 for layers 0/1 (Nc==BN), BN=64 for layer 2 (Nc=40, masked).
template <int BN>
__global__ __launch_bounds__(256) void gemm_f16(const f16* __restrict__ A,
                                                const f16* __restrict__ BT,
                                                f16* __restrict__ Cf16,
                                                float* __restrict__ Cf32,
                                                int M, int K, int Nc) {
    constexpr int NB = BN / 64;     // 16B B-chunks per thread per K-step
    constexpr int NT = BN / 64;     // n-tiles per wave
    __shared__ f16 As[32 * 40];     // [m][k], stride 40 halves (2-way banks=free)
    __shared__ f16 Bs[BN * 40];     // [n][k]
    int t = threadIdx.x;
    int bm = blockIdx.y * 32;

    int arow = t >> 3, akoff = (t & 7) * 4;
    bool a_ok = (bm + arow) < M;
    const f16* Ap = A + (size_t)(bm + arow) * K + akoff;

    int lane = t & 63, w = t >> 6;
    int fm = lane & 15, ks = (lane >> 4) * 8;

    f32x4 acc[2][NT] = {};
    uint2 ra;
    uint4 rb[NB];

    auto load_stage = [&](int k0) {
        ra = a_ok ? *(const uint2*)(Ap + k0) : make_uint2(0u, 0u);
#pragma unroll
        for (int j = 0; j < NB; ++j) {
            int c = j * 256 + t;
            int row = c >> 2, koff = (c & 3) * 8;
            rb[j] = (row < Nc) ? *(const uint4*)(BT + (size_t)row * K + k0 + koff)
                               : make_uint4(0u, 0u, 0u, 0u);
        }
    };

    load_stage(0);
    for (int k0 = 0; k0 < K; k0 += 32) {
        *(uint2*)&As[arow * 40 + akoff] = ra;
#pragma unroll
        for (int j = 0; j < NB; ++j) {
            int c = j * 256 + t;
            *(uint4*)&Bs[(c >> 2) * 40 + (c & 3) * 8] = rb[j];
        }
        __syncthreads();
        if (k0 + 32 < K) load_stage(k0 + 32);   // prefetch overlaps MFMA below
        f16x8 a0 = *(const f16x8*)&As[fm * 40 + ks];
        f16x8 a1 = *(const f16x8*)&As[(16 + fm) * 40 + ks];
#pragma unroll
        for (int nt = 0; nt < NT; ++nt) {
            f16x8 b = *(const f16x8*)&Bs[((w * NT + nt) * 16 + fm) * 40 + ks];
            acc[0][nt] = __builtin_amdgcn_mfma_f32_16x16x32_f16(a0, b, acc[0][nt], 0, 0, 0);
            acc[1][nt] = __builtin_amdgcn_mfma_f32_16x16x32_f16(a1, b, acc[1][nt], 0, 0, 0);
        }
        __syncthreads();
    }

    // C/D layout: col = lane&15, row = (lane>>4)*4 + reg
#pragma unroll
    for (int mt = 0; mt < 2; ++mt) {
        int grow = bm + mt * 16 + (lane >> 4) * 4;
#pragma unroll
        for (int nt = 0; nt < NT; ++nt) {
            int gcol = (w * NT + nt) * 16 + fm;
            if (gcol >= Nc) continue;
#pragma unroll
            for (int r = 0; r < 4; ++r) {
                if (grow + r < M) {
                    float v = acc[mt][nt][r];
                    if (Cf16) Cf16[(size_t)(grow + r) * Nc + gcol] = (f16)v;
                    if (Cf32) Cf32[(size_t)(grow + r) * Nc + gcol] = v;
                }
            }
        }
    }
}

// ---------- attention coefficients from fp16 hx (H=8, C=64) ----------
__global__ __launch_bounds__(256) void attn_f16_kernel(const f16* __restrict__ hx2,
                                                       const float* __restrict__ a_src,
                                                       const float* __restrict__ a_dst,
                                                       float* __restrict__ al_s,
                                                       float* __restrict__ al_d) {
    int wave = threadIdx.x >> 6, lane = threadIdx.x & 63;
    int n = blockIdx.x * 4 + wave;
    if (n >= NN) return;
    for (int h = 0; h < HH; ++h) {
        float v = (float)hx2[(size_t)n * HC + h * CC + lane];
        float vs = v * a_src[h * CC + lane];
        float vd = v * a_dst[h * CC + lane];
#pragma unroll
        for (int o = 32; o; o >>= 1) {
            vs += __shfl_down(vs, o);
            vd += __shfl_down(vd, o);
        }
        if (lane == 0) {
            al_s[n * HH + h] = vs;
            al_d[n * HH + h] = vd;
        }
    }
}

// ---------- fp32 attention coefficients (layer 2: H=1, C=40) ----------
__global__ __launch_bounds__(256) void attn_f32_kernel(const float* __restrict__ hx,
                                                       const float* __restrict__ a_src,
                                                       const float* __restrict__ a_dst,
                                                       float* __restrict__ al_s,
                                                       float* __restrict__ al_d,
                                                       int Hh, int Cc) {
    int wave = threadIdx.x >> 6, lane = threadIdx.x & 63;
    int n = blockIdx.x * 4 + wave;
    if (n >= NN) return;
    for (int h = 0; h < Hh; ++h) {
        float vs = 0.f, vd = 0.f;
        if (lane < Cc) {
            float v = hx[((size_t)n * Hh + h) * Cc + lane];
            vs = v * a_src[h * Cc + lane];
            vd = v * a_dst[h * Cc + lane];
        }
#pragma unroll
        for (int o = 32; o; o >>= 1) {
            vs += __shfl_down(vs, o);
            vd += __shfl_down(vd, o);
        }
        if (lane == 0) {
            al_s[n * Hh + h] = vs;
            al_d[n * Hh + h] = vd;
        }
    }
}

// ---------- fused softmax+aggregate+ELU (fp16 messages), unroll x4 ----------
__global__ __launch_bounds__(256) void aggregate_kernel(const f16* __restrict__ hx2,
                                                        const float* __restrict__ al_s,
                                                        const float* __restrict__ al_d,
                                                        const int* __restrict__ off,
                                                        const int* __restrict__ srcs,
                                                        const float* __restrict__ bias,
                                                        f16* __restrict__ outF) {
    int n = blockIdx.x;
    int tid = threadIdx.x;
    int ch = tid * 2;
    int h = ch >> 6;
    float ald = al_d[n * HH + h];
    int i0 = off[n], i1 = off[n + 1];
    float a0 = 0.f, a1 = 0.f, den = 0.f;
    int i = i0;
    for (; i + 4 <= i1; i += 4) {
        int s0 = srcs[i], s1 = srcs[i + 1], s2 = srcs[i + 2], s3 = srcs[i + 3];
        float e0 = al_s[s0 * HH + h], e1 = al_s[s1 * HH + h];
        float e2 = al_s[s2 * HH + h], e3 = al_s[s3 * HH + h];
        u32 v0 = *(const u32*)(hx2 + (size_t)s0 * HC + ch);
        u32 v1 = *(const u32*)(hx2 + (size_t)s1 * HC + ch);
        u32 v2 = *(const u32*)(hx2 + (size_t)s2 * HC + ch);
        u32 v3 = *(const u32*)(hx2 + (size_t)s3 * HC + ch);
        e0 += ald; e0 = e0 > 0.f ? e0 : 0.2f * e0;
        e1 += ald; e1 = e1 > 0.f ? e1 : 0.2f * e1;
        e2 += ald; e2 = e2 > 0.f ? e2 : 0.2f * e2;
        e3 += ald; e3 = e3 > 0.f ? e3 : 0.2f * e3;
        float w0 = __expf(e0), w1 = __expf(e1), w2 = __expf(e2), w3 = __expf(e3);
        a0 += w0 * h2f(v0 & 0xFFFF) + w1 * h2f(v1 & 0xFFFF) +
              w2 * h2f(v2 & 0xFFFF) + w3 * h2f(v3 & 0xFFFF);
        a1 += w0 * h2f(v0 >> 16) + w1 * h2f(v1 >> 16) +
              w2 * h2f(v2 >> 16) + w3 * h2f(v3 >> 16);
        den += w0 + w1 + w2 + w3;
    }
    for (; i < i1; ++i) {
        int s = srcs[i];
        float e = al_s[s * HH + h] + ald;
        e = e > 0.f ? e : 0.2f * e;
        float wgt = __expf(e);
        u32 v = *(const u32*)(hx2 + (size_t)s * HC + ch);
        a0 += wgt * h2f(v & 0xFFFF);
        a1 += wgt * h2f(v >> 16);
        den += wgt;
    }
    float inv = 1.f / (den + 1e-16f);
    float o0 = a0 * inv + bias[ch];
    float o1 = a1 * inv + bias[ch + 1];
    o0 = o0 > 0.f ? o0 : expm1f(o0);          // ELU
    o1 = o1 > 0.f ? o1 : expm1f(o1);
    u32 pack = (u32)__builtin_bit_cast(u16, (f16)o0) |
               ((u32)__builtin_bit_cast(u16, (f16)o1) << 16);
    *(u32*)(outF + (size_t)n * HC + ch) = pack;
}

// ---------- layer 2 aggregate (H=1,C=40), fp32, no ELU, unroll x4 ----------
__global__ __launch_bounds__(64) void aggregate2_kernel(const float* __restrict__ hx,
                                                        const float* __restrict__ al_s,
                                                        const float* __restrict__ al_d,
                                                        const int* __restrict__ off,
                                                        const int* __restrict__ srcs,
                                                        const float* __restrict__ bias,
                                                        float* __restrict__ out) {
    int n = blockIdx.x;
    int c = threadIdx.x;
    float ald = al_d[n];
    int i0 = off[n], i1 = off[n + 1];
    float acc = 0.f, den = 0.f;
    int i = i0;
    for (; i + 4 <= i1; i += 4) {
        int s0 = srcs[i], s1 = srcs[i + 1], s2 = srcs[i + 2], s3 = srcs[i + 3];
        float e0 = al_s[s0], e1 = al_s[s1], e2 = al_s[s2], e3 = al_s[s3];
        float v0 = 0.f, v1 = 0.f, v2 = 0.f, v3 = 0.f;
        if (c < NCLS) {
            v0 = hx[(size_t)s0 * NCLS + c];
            v1 = hx[(size_t)s1 * NCLS + c];
            v2 = hx[(size_t)s2 * NCLS + c];
            v3 = hx[(size_t)s3 * NCLS + c];
        }
        e0 += ald; e0 = e0 > 0.f ? e0 : 0.2f * e0;
        e1 += ald; e1 = e1 > 0.f ? e1 : 0.2f * e1;
        e2 += ald; e2 = e2 > 0.f ? e2 : 0.2f * e2;
        e3 += ald; e3 = e3 > 0.f ? e3 : 0.2f * e3;
        float w0 = __expf(e0), w1 = __expf(e1), w2 = __expf(e2), w3 = __expf(e3);
        acc += w0 * v0 + w1 * v1 + w2 * v2 + w3 * v3;
        den += w0 + w1 + w2 + w3;
    }
    for (; i < i1; ++i) {
        int s = srcs[i];
        float e = al_s[s] + ald;
        e = e > 0.f ? e : 0.2f * e;
        float wgt = __expf(e);
        if (c < NCLS) acc += wgt * hx[(size_t)s * NCLS + c];
        den += wgt;
    }
    if (c < NCLS) out[(size_t)n * NCLS + c] = acc / (den + 1e-16f) + bias[c];
}

extern "C" void kernel_launch(void* const* d_in, const int* in_sizes, int n_in,
                              void* d_out, int out_size, void* d_ws, size_t ws_size,
                              hipStream_t stream) {
    const float* x   = (const float*)d_in[0];
    const int*   ei  = (const int*)  d_in[1];
    const float* W0  = (const float*)d_in[2];
    const float* as0 = (const float*)d_in[3];
    const float* ad0 = (const float*)d_in[4];
    const float* b0  = (const float*)d_in[5];
    const float* W1  = (const float*)d_in[6];
    const float* as1 = (const float*)d_in[7];
    const float* ad1 = (const float*)d_in[8];
    const float* b1  = (const float*)d_in[9];
    const float* W2  = (const float*)d_in[10];
    const float* as2 = (const float*)d_in[11];
    const float* ad2 = (const float*)d_in[12];
    const float* b2  = (const float*)d_in[13];
    float* out = (float*)d_out;

    char* p = (char*)d_ws;
    int* deg    = (int*)p; p += 40000;
    int* cursor = (int*)p; p += 40000;
    int* off    = (int*)p; p += 40016;
    int* srcs   = (int*)p; p += 680000;
    f16* xf  = (f16*)p; p += 5120000;
    f16* w0T = (f16*)p; p += 262144;
    f16* w1T = (f16*)p; p += 524288;
    f16* w2T = (f16*)p; p += 40960;
    f16* hx2 = (f16*)p; p += 10240000;
    f16* fA  = (f16*)p; p += 10240000;
    f16* fB  = (f16*)p; p += 10240000;
    float* hx40 = (float*)p; p += 1600000;
    float* alsb = (float*)p; p += 320000;
    float* aldb = (float*)p; p += 320000;

    // CSR by dst
    zero_int<<<(NN + 255) / 256, 256, 0, stream>>>(deg, NN);
    hist_kernel<<<(ET + 255) / 256, 256, 0, stream>>>(ei, deg);
    scan_kernel<<<1, 1024, 0, stream>>>(deg, off, cursor);
    scatter_kernel<<<(ET + 255) / 256, 256, 0, stream>>>(ei, cursor, srcs);

    // conversions
    conv_f16<<<(NN * FIN / 4 + 255) / 256, 256, 0, stream>>>(x, xf, NN * FIN / 4);
    convT_f16<<<(HC * FIN + 255) / 256, 256, 0, stream>>>(W0, w0T, 8, HC);
    convT_f16<<<(HC * HC + 255) / 256, 256, 0, stream>>>(W1, w1T, 9, HC);
    convT_f16<<<(NCLS * HC + 255) / 256, 256, 0, stream>>>(W2, w2T, 9, NCLS);

    dim3 gA(1, (NN + 31) / 32);
    // layer 0
    gemm_f16<512><<<gA, 256, 0, stream>>>(xf, w0T, hx2, (float*)nullptr, NN, FIN, HC);
    attn_f16_kernel<<<(NN + 3) / 4, 256, 0, stream>>>(hx2, as0, ad0, alsb, aldb);
    aggregate_kernel<<<NN, 256, 0, stream>>>(hx2, alsb, aldb, off, srcs, b0, fA);
    // layer 1
    gemm_f16<512><<<gA, 256, 0, stream>>>(fA, w1T, hx2, (float*)nullptr, NN, HC, HC);
    attn_f16_kernel<<<(NN + 3) / 4, 256, 0, stream>>>(hx2, as1, ad1, alsb, aldb);
    aggregate_kernel<<<NN, 256, 0, stream>>>(hx2, alsb, aldb, off, srcs, b1, fB);
    // layer 2 (fp32 output path)
    gemm_f16<64><<<gA, 256, 0, stream>>>(fB, w2T, (f16*)nullptr, hx40, NN, HC, NCLS);
    attn_f32_kernel<<<(NN + 3) / 4, 256, 0, stream>>>(hx40, as2, ad2, alsb, aldb, 1, NCLS);
    aggregate2_kernel<<<NN, 64, 0, stream>>>(hx40, alsb, aldb, off, srcs, b2, out);
}